// Round 5
// baseline (70936.292 us; speedup 1.0000x reference)
//
#include <hip/hip_runtime.h>
#include <math.h>

#define Bsz 512
#define Tsz 1024
#define Vsz 27
#define Hsz 512
#define NBLK 256
#define NT 512     // 8 waves, 2 per SIMD
#define BT 64      // batch rows per group (8 groups)
#define HPc 16     // h' cols per block (32 j-blocks)
#define NG 48      // gate rows per block = 3*HPc
#define WPAD 516   // padded K-stride for W_hh tile

// swizzled float4 index within a 64x16(quads) h tile: involution c4 ^= (r&15)
__device__ __forceinline__ int hs_q(int r, int c4) {
    return (r << 4) + (c4 ^ (r & 15));
}

__device__ __forceinline__ void gload_lds16(const float* src, float* dst) {
    __builtin_amdgcn_global_load_lds(
        (const __attribute__((address_space(1))) unsigned int*)src,
        (__attribute__((address_space(3))) unsigned int*)dst, 16, 0, 0);
}

__global__ void init_ws_kernel(float* __restrict__ hbuf, unsigned* __restrict__ cnt) {
    int i = blockIdx.x * 256 + threadIdx.x;
    ((float4*)hbuf)[i] = make_float4(0.f, 0.f, 0.f, 0.f);
    if (blockIdx.x == 0) cnt[threadIdx.x] = 0u;
}

// Relaxed-poll barrier: exactly ONE release fence before the add and ONE
// acquire fence after the spin (R4's ACQUIRE-in-loop emitted buffer_inv sc1
// per poll -> XCD-wide L2 wipe dozens of times/step; prime slowdown suspect).
__device__ __forceinline__ void group_barrier(unsigned* c, unsigned target) {
    __syncthreads();
    if (threadIdx.x == 0) {
        __threadfence();  // release: h stores reach coherence point
        __hip_atomic_fetch_add(c, 1u, __ATOMIC_RELAXED, __HIP_MEMORY_SCOPE_AGENT);
        while (__hip_atomic_load(c, __ATOMIC_RELAXED, __HIP_MEMORY_SCOPE_AGENT) < target)
            __builtin_amdgcn_s_sleep(8);
        __threadfence();  // acquire: invalidate stale L2 once
    }
    __syncthreads();
}

__global__ __launch_bounds__(NT, 2) void gru_persist(
    const float* __restrict__ x, const float* __restrict__ W_ih,
    const float* __restrict__ W_hh, const float* __restrict__ b_ih,
    const float* __restrict__ b_hh, const float* __restrict__ W_dec,
    const float* __restrict__ b_dec, float* __restrict__ hbuf,
    unsigned* __restrict__ cnt, float* __restrict__ out)
{
    __shared__ float ws[NG][WPAD];      // persistent W_hh slice (97 KB)
    __shared__ float wi[NG][28];
    __shared__ float xs[BT][28];
    __shared__ float wd[Hsz];           // W_dec row v=j (j<27)
    __shared__ float bih[NG], bhh[NG];
    __shared__ float hsf[2][64 * 64];   // double-buffered swizzled h chunk (+ red scratch)

    const int tid = threadIdx.x;
    const int bt  = blockIdx.x >> 5;    // batch group 0..7
    const int j   = blockIdx.x & 31;    // h' tile 0..31
    const int b0  = bt * BT;
    const int g0  = j * HPc;

    // ---- persistent staging (once) ----
    for (int idx = tid; idx < NG * (Hsz / 4); idx += NT) {
        int row = idx >> 7, c4 = idx & 127;
        int grow = (row < 16) ? (g0 + row) : (row < 32 ? Hsz + g0 + row - 16 : 2 * Hsz + g0 + row - 32);
        *(float4*)&ws[row][c4 << 2] = *(const float4*)&W_hh[(size_t)grow * Hsz + (c4 << 2)];
    }
    for (int idx = tid; idx < NG * Vsz; idx += NT) {
        int row = idx / Vsz, v = idx - row * Vsz;
        int grow = (row < 16) ? (g0 + row) : (row < 32 ? Hsz + g0 + row - 16 : 2 * Hsz + g0 + row - 32);
        wi[row][v] = W_ih[grow * Vsz + v];
    }
    if (tid < NG) {
        int grow = (tid < 16) ? (g0 + tid) : (tid < 32 ? Hsz + g0 + tid - 16 : 2 * Hsz + g0 + tid - 32);
        bih[tid] = b_ih[grow];
        bhh[tid] = b_hh[grow];
    }
    if (j < Vsz)
        for (int k = tid; k < Hsz; k += NT) wd[k] = W_dec[j * Hsz + k];
    const float bdec_s = (j < Vsz) ? b_dec[j] : 0.f;

    const int kh = tid >> 8;            // K-half 0/1 (k4 0-7 vs 8-15 per chunk)
    const int th = tid & 255;
    const int hp = th & 15;             // h' col within tile
    const int bq = (th >> 4) << 2;      // 4 batch rows per thread
    const int db = tid >> 3, dk = tid & 7;   // decode mapping (8-way K-split)
    const int wv = tid >> 6, ln = tid & 63;  // wave id (0..7) / lane
    unsigned* mycnt = cnt + bt * 32;
    const int cj  = j >> 2;                        // chunk holding own h' slice
    const int c4o = ((j & 3) << 2) + (hp >> 2);
    const int eo  = hp & 3;

    for (int i = 0; i <= Tsz; ++i) {
        const float* hprev = hbuf + (size_t)(i & 1) * (Bsz * Hsz);

        // issue chunk 0 into hsf[0] (pre-swizzled global source, linear LDS dest)
        {
            float* dstb = &hsf[0][0];
            #pragma unroll
            for (int ii = 0; ii < 2; ++ii) {
                int rb = ((wv << 1) + ii) << 2;        // 4-row slab per wave-inst
                int r  = rb + (ln >> 4);
                int c4g = (ln & 15) ^ (r & 15);
                gload_lds16(hprev + (size_t)(b0 + r) * Hsz + (c4g << 2),
                            dstb + (rb << 6));
            }
        }
        if (i < Tsz) {
            for (int idx = tid; idx < BT * Vsz; idx += NT) {
                int r = idx / Vsz, v = idx - r * Vsz;
                xs[r][v] = x[(size_t)(b0 + r) * (Tsz * Vsz) + (size_t)i * Vsz + v];
            }
        }
        __syncthreads();

        // ---- gi = x . W_ih^T + b_ih (K=27), from LDS ----
        float gr[4], gz[4], gn[4];
        #pragma unroll
        for (int q = 0; q < 4; ++q) { gr[q] = bih[hp]; gz[q] = bih[16 + hp]; gn[q] = bih[32 + hp]; }
        if (i < Tsz) {
            for (int v = 0; v < Vsz; ++v) {
                float wr_ = wi[hp][v], wz_ = wi[16 + hp][v], wn_ = wi[32 + hp][v];
                #pragma unroll
                for (int q = 0; q < 4; ++q) {
                    float xv = xs[bq + q][v];
                    gr[q] += xv * wr_; gz[q] += xv * wz_; gn[q] += xv * wn_;
                }
            }
        }

        float accr[4] = {0,0,0,0}, accz[4] = {0,0,0,0}, accn[4] = {0,0,0,0};
        float hkeep[4] = {0,0,0,0};
        float dec = 0.f;
        const bool doDec = (i > 0) && (j < Vsz);

        for (int c = 0; c < 8; ++c) {
            const float* hsc = &hsf[c & 1][0];
            if (c < 7) {   // prefetch next chunk
                float* dstb = &hsf[(c + 1) & 1][0];
                const int kc = (c + 1) << 6;
                #pragma unroll
                for (int ii = 0; ii < 2; ++ii) {
                    int rb = ((wv << 1) + ii) << 2;
                    int r  = rb + (ln >> 4);
                    int c4g = (ln & 15) ^ (r & 15);
                    gload_lds16(hprev + (size_t)(b0 + r) * Hsz + kc + (c4g << 2),
                                dstb + (rb << 6));
                }
            }
            if (i < Tsz) {
                const int k4lo = kh << 3;
                #pragma unroll
                for (int k4i = 0; k4i < 8; ++k4i) {
                    const int k4 = k4lo + k4i;
                    const int kk = (c << 6) + (k4 << 2);
                    float4 wr4 = *(const float4*)&ws[hp][kk];
                    float4 wz4 = *(const float4*)&ws[16 + hp][kk];
                    float4 wn4 = *(const float4*)&ws[32 + hp][kk];
                    #pragma unroll
                    for (int q = 0; q < 4; ++q) {
                        float4 hv = *(const float4*)&hsc[hs_q(bq + q, k4) << 2];
                        accr[q] += hv.x * wr4.x + hv.y * wr4.y + hv.z * wr4.z + hv.w * wr4.w;
                        accz[q] += hv.x * wz4.x + hv.y * wz4.y + hv.z * wz4.z + hv.w * wz4.w;
                        accn[q] += hv.x * wn4.x + hv.y * wn4.y + hv.z * wn4.z + hv.w * wn4.w;
                    }
                }
                if (c == cj && kh == 0) {
                    #pragma unroll
                    for (int q = 0; q < 4; ++q)
                        hkeep[q] = hsc[(hs_q(bq + q, c4o) << 2) + eo];
                }
            }
            if (doDec) {   // decode h_{i-1} for v=j, 8-way split-K per batch row
                #pragma unroll
                for (int ii = 0; ii < 2; ++ii) {
                    int c4 = (dk << 1) + ii;
                    float4 hv = *(const float4*)&hsc[hs_q(db, c4) << 2];
                    float4 wv4 = *(const float4*)&wd[(c << 6) + (c4 << 2)];
                    dec += hv.x * wv4.x + hv.y * wv4.y + hv.z * wv4.z + hv.w * wv4.w;
                }
            }
            if (c < 7) __syncthreads();
        }

        // ---- K-half reduction through hsf[0] (dead after chunk 6) ----
        if (kh == 1) {
            float4* p = (float4*)(&hsf[0][0] + th * 12);
            p[0] = make_float4(accr[0], accr[1], accr[2], accr[3]);
            p[1] = make_float4(accz[0], accz[1], accz[2], accz[3]);
            p[2] = make_float4(accn[0], accn[1], accn[2], accn[3]);
        }
        __syncthreads();
        if (kh == 0) {
            float4* p = (float4*)(&hsf[0][0] + th * 12);
            float4 a = p[0], b = p[1], cc = p[2];
            accr[0] += a.x; accr[1] += a.y; accr[2] += a.z; accr[3] += a.w;
            accz[0] += b.x; accz[1] += b.y; accz[2] += b.z; accz[3] += b.w;
            accn[0] += cc.x; accn[1] += cc.y; accn[2] += cc.z; accn[3] += cc.w;
        }

        // ---- gates + h update (K-half 0 only) ----
        if (i < Tsz && kh == 0) {
            float* hnext = hbuf + (size_t)((i + 1) & 1) * (Bsz * Hsz);
            #pragma unroll
            for (int q = 0; q < 4; ++q) {
                float hr = accr[q] + bhh[hp];
                float hz = accz[q] + bhh[16 + hp];
                float hn = accn[q] + bhh[32 + hp];
                float rg = 1.f / (1.f + expf(-(gr[q] + hr)));
                float zg = 1.f / (1.f + expf(-(gz[q] + hz)));
                float ng = tanhf(gn[q] + rg * hn);
                hnext[(size_t)(b0 + bq + q) * Hsz + g0 + hp] = (1.f - zg) * ng + zg * hkeep[q];
            }
        }
        if (doDec) {
            dec += __shfl_xor(dec, 1);
            dec += __shfl_xor(dec, 2);
            dec += __shfl_xor(dec, 4);
            if (dk == 0)
                out[(size_t)(b0 + db) * (Tsz * Vsz) + (size_t)(i - 1) * Vsz + j] = dec + bdec_s;
        }
        if (i < Tsz) group_barrier(mycnt, 32u * (unsigned)(i + 1));
    }
}

extern "C" void kernel_launch(void* const* d_in, const int* in_sizes, int n_in,
                              void* d_out, int out_size, void* d_ws, size_t ws_size,
                              hipStream_t stream) {
    const float* x     = (const float*)d_in[0];
    const float* W_ih  = (const float*)d_in[1];
    const float* W_hh  = (const float*)d_in[2];
    const float* b_ih  = (const float*)d_in[3];
    const float* b_hh  = (const float*)d_in[4];
    const float* W_dec = (const float*)d_in[5];
    const float* b_dec = (const float*)d_in[6];
    float* out  = (float*)d_out;
    float* hbuf = (float*)d_ws;
    unsigned* cnt = (unsigned*)((char*)d_ws + (size_t)2 * Bsz * Hsz * sizeof(float));

    init_ws_kernel<<<256, 256, 0, stream>>>(hbuf, cnt);

    // Plain launch: 143 KB LDS -> 1 block/CU, grid == 256 == CU count ->
    // all blocks co-resident; hand-rolled group barriers cannot deadlock.
    gru_persist<<<dim3(NBLK), dim3(NT), 0, stream>>>(
        x, W_ih, W_hh, b_ih, b_hh, W_dec, b_dec, hbuf, cnt, out);
}

// Round 6
// 65460.413 us; speedup vs baseline: 1.0837x; 1.0837x over previous
//
#include <hip/hip_runtime.h>
#include <math.h>

#define Bsz 512
#define Tsz 1024
#define Vsz 27
#define Hsz 512
#define NBLK 256
#define NT 512     // 8 waves, 2 per SIMD
#define BT 64      // batch rows per group (8 groups)
#define HPc 16     // h' cols per block (32 j-blocks)
#define NG 48      // gate rows per block = 3*HPc
#define WPAD 516   // padded K-stride for W_hh tile

// CPol bits (gfx940+/gfx950): bit0 = SC0 (L1 bypass), bit4 = SC1 (L2 bypass /
// device-coherence-point). 0x11 = sc0|sc1: load served from L3 (memory-side,
// cross-XCD coherent), no L2 fill, no stale-L2 hit.
#define AUX_SC0_SC1 0x11

// swizzled float4 index within a 64x16(quads) h tile: involution c4 ^= (r&15)
__device__ __forceinline__ int hs_q(int r, int c4) {
    return (r << 4) + (c4 ^ (r & 15));
}

__device__ __forceinline__ void gload_lds16_cc(const float* src, float* dst) {
    __builtin_amdgcn_global_load_lds(
        (const __attribute__((address_space(1))) unsigned int*)src,
        (__attribute__((address_space(3))) unsigned int*)dst, 16, 0, AUX_SC0_SC1);
}

// write-through store: past L1 and L2 straight to the coherence point (L3).
// h lines are thus never dirty in any XCD's L2 -> sc1 readers always current.
__device__ __forceinline__ void store_wt(float* p, float v) {
    asm volatile("global_store_dword %0, %1, off sc0 sc1"
                 :: "v"(p), "v"(v) : "memory");
}

__global__ void init_ws_kernel(float* __restrict__ hbuf, unsigned* __restrict__ cnt) {
    int i = blockIdx.x * 256 + threadIdx.x;
    ((float4*)hbuf)[i] = make_float4(0.f, 0.f, 0.f, 0.f);
    if (blockIdx.x == 0) cnt[threadIdx.x] = 0u;
    // end-of-dispatch implicit release flushes these zeros to the coherence
    // point, so gru_persist's sc1 reads of step-0 h see them.
}

// Fence-free group barrier. Correctness: every wave executed
// s_waitcnt vmcnt(0) after its write-through h stores BEFORE entering this,
// so h is at the coherence point when the flag increments. Readers bypass L2.
// No buffer_wbl2 / buffer_inv -> L2 stays warm for x/weights.
__device__ __forceinline__ void group_barrier(unsigned* c, unsigned target) {
    __syncthreads();
    if (threadIdx.x == 0) {
        __hip_atomic_fetch_add(c, 1u, __ATOMIC_RELAXED, __HIP_MEMORY_SCOPE_AGENT);
        while (__hip_atomic_load(c, __ATOMIC_RELAXED, __HIP_MEMORY_SCOPE_AGENT) < target)
            __builtin_amdgcn_s_sleep(2);
    }
    __syncthreads();
}

__global__ __launch_bounds__(NT, 2) void gru_persist(
    const float* __restrict__ x, const float* __restrict__ W_ih,
    const float* __restrict__ W_hh, const float* __restrict__ b_ih,
    const float* __restrict__ b_hh, const float* __restrict__ W_dec,
    const float* __restrict__ b_dec, float* __restrict__ hbuf,
    unsigned* __restrict__ cnt, float* __restrict__ out)
{
    __shared__ float ws[NG][WPAD];      // persistent W_hh slice (97 KB)
    __shared__ float wi[NG][28];
    __shared__ float xs[BT][28];
    __shared__ float wd[Hsz];           // W_dec row v=j (j<27)
    __shared__ float bih[NG], bhh[NG];
    __shared__ float hsf[2][64 * 64];   // double-buffered swizzled h chunk (+ red scratch)

    const int tid = threadIdx.x;
    const int bt  = blockIdx.x >> 5;    // batch group 0..7
    const int j   = blockIdx.x & 31;    // h' tile 0..31
    const int b0  = bt * BT;
    const int g0  = j * HPc;

    // ---- persistent staging (once) ----
    for (int idx = tid; idx < NG * (Hsz / 4); idx += NT) {
        int row = idx >> 7, c4 = idx & 127;
        int grow = (row < 16) ? (g0 + row) : (row < 32 ? Hsz + g0 + row - 16 : 2 * Hsz + g0 + row - 32);
        *(float4*)&ws[row][c4 << 2] = *(const float4*)&W_hh[(size_t)grow * Hsz + (c4 << 2)];
    }
    for (int idx = tid; idx < NG * Vsz; idx += NT) {
        int row = idx / Vsz, v = idx - row * Vsz;
        int grow = (row < 16) ? (g0 + row) : (row < 32 ? Hsz + g0 + row - 16 : 2 * Hsz + g0 + row - 32);
        wi[row][v] = W_ih[grow * Vsz + v];
    }
    if (tid < NG) {
        int grow = (tid < 16) ? (g0 + tid) : (tid < 32 ? Hsz + g0 + tid - 16 : 2 * Hsz + g0 + tid - 32);
        bih[tid] = b_ih[grow];
        bhh[tid] = b_hh[grow];
    }
    if (j < Vsz)
        for (int k = tid; k < Hsz; k += NT) wd[k] = W_dec[j * Hsz + k];
    const float bdec_s = (j < Vsz) ? b_dec[j] : 0.f;

    const int kh = tid >> 8;            // K-half 0/1 (k4 0-7 vs 8-15 per chunk)
    const int th = tid & 255;
    const int hp = th & 15;             // h' col within tile
    const int bq = (th >> 4) << 2;      // 4 batch rows per thread
    const int db = tid >> 3, dk = tid & 7;   // decode mapping (8-way K-split)
    const int wv = tid >> 6, ln = tid & 63;  // wave id (0..7) / lane
    unsigned* mycnt = cnt + bt * 32;
    const int cj  = j >> 2;                        // chunk holding own h' slice
    const int c4o = ((j & 3) << 2) + (hp >> 2);
    const int eo  = hp & 3;

    for (int i = 0; i <= Tsz; ++i) {
        const float* hprev = hbuf + (size_t)(i & 1) * (Bsz * Hsz);

        // issue chunk 0 into hsf[0] (pre-swizzled global source, linear LDS dest)
        {
            float* dstb = &hsf[0][0];
            #pragma unroll
            for (int ii = 0; ii < 2; ++ii) {
                int rb = ((wv << 1) + ii) << 2;        // 4-row slab per wave-inst
                int r  = rb + (ln >> 4);
                int c4g = (ln & 15) ^ (r & 15);
                gload_lds16_cc(hprev + (size_t)(b0 + r) * Hsz + (c4g << 2),
                               dstb + (rb << 6));
            }
        }
        if (i < Tsz) {
            for (int idx = tid; idx < BT * Vsz; idx += NT) {
                int r = idx / Vsz, v = idx - r * Vsz;
                xs[r][v] = x[(size_t)(b0 + r) * (Tsz * Vsz) + (size_t)i * Vsz + v];
            }
        }
        __syncthreads();

        // ---- gi = x . W_ih^T + b_ih (K=27), from LDS ----
        float gr[4], gz[4], gn[4];
        #pragma unroll
        for (int q = 0; q < 4; ++q) { gr[q] = bih[hp]; gz[q] = bih[16 + hp]; gn[q] = bih[32 + hp]; }
        if (i < Tsz) {
            for (int v = 0; v < Vsz; ++v) {
                float wr_ = wi[hp][v], wz_ = wi[16 + hp][v], wn_ = wi[32 + hp][v];
                #pragma unroll
                for (int q = 0; q < 4; ++q) {
                    float xv = xs[bq + q][v];
                    gr[q] += xv * wr_; gz[q] += xv * wz_; gn[q] += xv * wn_;
                }
            }
        }

        float accr[4] = {0,0,0,0}, accz[4] = {0,0,0,0}, accn[4] = {0,0,0,0};
        float hkeep[4] = {0,0,0,0};
        float dec = 0.f;
        const bool doDec = (i > 0) && (j < Vsz);

        for (int c = 0; c < 8; ++c) {
            const float* hsc = &hsf[c & 1][0];
            if (c < 7) {   // prefetch next chunk
                float* dstb = &hsf[(c + 1) & 1][0];
                const int kc = (c + 1) << 6;
                #pragma unroll
                for (int ii = 0; ii < 2; ++ii) {
                    int rb = ((wv << 1) + ii) << 2;
                    int r  = rb + (ln >> 4);
                    int c4g = (ln & 15) ^ (r & 15);
                    gload_lds16_cc(hprev + (size_t)(b0 + r) * Hsz + kc + (c4g << 2),
                                   dstb + (rb << 6));
                }
            }
            if (i < Tsz) {
                const int k4lo = kh << 3;
                #pragma unroll
                for (int k4i = 0; k4i < 8; ++k4i) {
                    const int k4 = k4lo + k4i;
                    const int kk = (c << 6) + (k4 << 2);
                    float4 wr4 = *(const float4*)&ws[hp][kk];
                    float4 wz4 = *(const float4*)&ws[16 + hp][kk];
                    float4 wn4 = *(const float4*)&ws[32 + hp][kk];
                    #pragma unroll
                    for (int q = 0; q < 4; ++q) {
                        float4 hv = *(const float4*)&hsc[hs_q(bq + q, k4) << 2];
                        accr[q] += hv.x * wr4.x + hv.y * wr4.y + hv.z * wr4.z + hv.w * wr4.w;
                        accz[q] += hv.x * wz4.x + hv.y * wz4.y + hv.z * wz4.z + hv.w * wz4.w;
                        accn[q] += hv.x * wn4.x + hv.y * wn4.y + hv.z * wn4.z + hv.w * wn4.w;
                    }
                }
                if (c == cj && kh == 0) {
                    #pragma unroll
                    for (int q = 0; q < 4; ++q)
                        hkeep[q] = hsc[(hs_q(bq + q, c4o) << 2) + eo];
                }
            }
            if (doDec) {   // decode h_{i-1} for v=j, 8-way split-K per batch row
                #pragma unroll
                for (int ii = 0; ii < 2; ++ii) {
                    int c4 = (dk << 1) + ii;
                    float4 hv = *(const float4*)&hsc[hs_q(db, c4) << 2];
                    float4 wv4 = *(const float4*)&wd[(c << 6) + (c4 << 2)];
                    dec += hv.x * wv4.x + hv.y * wv4.y + hv.z * wv4.z + hv.w * wv4.w;
                }
            }
            if (c < 7) __syncthreads();
        }

        // ---- K-half reduction through hsf[0] (dead after chunk 6) ----
        if (kh == 1) {
            float4* p = (float4*)(&hsf[0][0] + th * 12);
            p[0] = make_float4(accr[0], accr[1], accr[2], accr[3]);
            p[1] = make_float4(accz[0], accz[1], accz[2], accz[3]);
            p[2] = make_float4(accn[0], accn[1], accn[2], accn[3]);
        }
        __syncthreads();
        if (kh == 0) {
            float4* p = (float4*)(&hsf[0][0] + th * 12);
            float4 a = p[0], b = p[1], cc = p[2];
            accr[0] += a.x; accr[1] += a.y; accr[2] += a.z; accr[3] += a.w;
            accz[0] += b.x; accz[1] += b.y; accz[2] += b.z; accz[3] += b.w;
            accn[0] += cc.x; accn[1] += cc.y; accn[2] += cc.z; accn[3] += cc.w;
        }

        // ---- gates + h update (K-half 0 only), write-through stores ----
        if (i < Tsz && kh == 0) {
            float* hnext = hbuf + (size_t)((i + 1) & 1) * (Bsz * Hsz);
            #pragma unroll
            for (int q = 0; q < 4; ++q) {
                float hr = accr[q] + bhh[hp];
                float hz = accz[q] + bhh[16 + hp];
                float hn = accn[q] + bhh[32 + hp];
                float rg = 1.f / (1.f + expf(-(gr[q] + hr)));
                float zg = 1.f / (1.f + expf(-(gz[q] + hz)));
                float ng = tanhf(gn[q] + rg * hn);
                store_wt(&hnext[(size_t)(b0 + bq + q) * Hsz + g0 + hp],
                         (1.f - zg) * ng + zg * hkeep[q]);
            }
        }
        if (doDec) {
            dec += __shfl_xor(dec, 1);
            dec += __shfl_xor(dec, 2);
            dec += __shfl_xor(dec, 4);
            if (dk == 0)
                out[(size_t)(b0 + db) * (Tsz * Vsz) + (size_t)(i - 1) * Vsz + j] = dec + bdec_s;
        }
        if (i < Tsz) {
            // own-wave write-through stores must reach the coherence point
            // before this block's barrier arrival.
            asm volatile("s_waitcnt vmcnt(0)" ::: "memory");
            group_barrier(mycnt, 32u * (unsigned)(i + 1));
        }
    }
}

extern "C" void kernel_launch(void* const* d_in, const int* in_sizes, int n_in,
                              void* d_out, int out_size, void* d_ws, size_t ws_size,
                              hipStream_t stream) {
    const float* x     = (const float*)d_in[0];
    const float* W_ih  = (const float*)d_in[1];
    const float* W_hh  = (const float*)d_in[2];
    const float* b_ih  = (const float*)d_in[3];
    const float* b_hh  = (const float*)d_in[4];
    const float* W_dec = (const float*)d_in[5];
    const float* b_dec = (const float*)d_in[6];
    float* out  = (float*)d_out;
    float* hbuf = (float*)d_ws;
    unsigned* cnt = (unsigned*)((char*)d_ws + (size_t)2 * Bsz * Hsz * sizeof(float));

    init_ws_kernel<<<256, 256, 0, stream>>>(hbuf, cnt);

    // Plain launch: 143 KB LDS -> 1 block/CU, grid == 256 == CU count ->
    // all blocks co-resident; hand-rolled group barriers cannot deadlock.
    gru_persist<<<dim3(NBLK), dim3(NT), 0, stream>>>(
        x, W_ih, W_hh, b_ih, b_hh, W_dec, b_dec, hbuf, cnt, out);
}

// Round 7
// 25938.251 us; speedup vs baseline: 2.7348x; 2.5237x over previous
//
#include <hip/hip_runtime.h>
#include <math.h>

#define Bsz 512
#define Tsz 1024
#define Vsz 27
#define Hsz 512
#define NBLK 256
#define NT 512      // 8 waves; wave = M-tile (16 batch rows)
#define BT 128      // batch rows per group (4 groups of 64 blocks)
#define HPc 8       // h' cols per block (64 j-tiles)
#define NG 24       // 3*HPc gate rows per block
#define WROW 576    // ushort stride of W planes (72 x 16B groups, covers swizzle to 71)
#define WDROW 512   // ushort stride of W_dec plane

typedef float f32x4 __attribute__((ext_vector_type(4)));
typedef short s16x8 __attribute__((ext_vector_type(8)));
#define MFMA __builtin_amdgcn_mfma_f32_16x16x32_bf16

__device__ __forceinline__ unsigned short btrunc(float x) {          // bf16 RTZ bits
    return (unsigned short)(__float_as_uint(x) >> 16);
}
__device__ __forceinline__ float bup(unsigned short b) {             // bf16 bits -> f32
    return __uint_as_float(((unsigned)b) << 16);
}
__device__ __forceinline__ unsigned short brne(float x) {            // bf16 RNE bits
    unsigned u = __float_as_uint(x);
    return (unsigned short)((u + 0x7FFFu + ((u >> 16) & 1u)) >> 16);
}
// write-through store: h never dirty in any XCD L2 -> L3 always current (R6-proven)
__device__ __forceinline__ void store_wt(float* p, float v) {
    asm volatile("global_store_dword %0, %1, off sc0 sc1" :: "v"(p), "v"(v) : "memory");
}
__device__ __forceinline__ void gload_lds16(const float* src, float* dst) {
    __builtin_amdgcn_global_load_lds(
        (const __attribute__((address_space(1))) unsigned int*)src,
        (__attribute__((address_space(3))) unsigned int*)dst, 16, 0, 0);
}

__global__ void init_ws_kernel(float* __restrict__ hbuf, unsigned* __restrict__ cnt) {
    int i = blockIdx.x * 256 + threadIdx.x;
    ((float4*)hbuf)[i] = make_float4(0.f, 0.f, 0.f, 0.f);
    if (blockIdx.x == 0) cnt[threadIdx.x] = 0u;
}

// WT stores drained (vmcnt0) before arrival; acquire fence (L1/L2 inv) after spin.
__device__ __forceinline__ void group_barrier(unsigned* c, unsigned target) {
    __syncthreads();
    if (threadIdx.x == 0) {
        __hip_atomic_fetch_add(c, 1u, __ATOMIC_RELAXED, __HIP_MEMORY_SCOPE_AGENT);
        while (__hip_atomic_load(c, __ATOMIC_RELAXED, __HIP_MEMORY_SCOPE_AGENT) < target)
            __builtin_amdgcn_s_sleep(2);
        __threadfence();   // acquire side: invalidate stale L1/L2 (R4-proven pattern)
    }
    __syncthreads();
}

__global__ __launch_bounds__(NT, 2) void gru_persist(
    const float* __restrict__ x, const float* __restrict__ W_ih,
    const float* __restrict__ W_hh, const float* __restrict__ b_ih,
    const float* __restrict__ b_hh, const float* __restrict__ W_dec,
    const float* __restrict__ b_dec, float* __restrict__ hbuf,
    unsigned* __restrict__ cnt, float* __restrict__ out)
{
    // bf16 triple-split W planes, K = 544 (512 h-cols | 27 x-cols | 5 zero pad)
    __shared__ unsigned short Wp0[NG * WROW], Wp1[NG * WROW], Wp2[NG * WROW];
    __shared__ unsigned short Wdp[Vsz * WDROW];        // W_dec RNE bf16 plane
    __shared__ float Abuf[2][BT * 32];                 // staged h/x chunks (XOR-swizzled)
    __shared__ float bihL[NG], bhhL[NG];

    const int tid = threadIdx.x;
    const int bt  = blockIdx.x & 3;     // batch group 0..3 (XCD-locality heuristic)
    const int j   = blockIdx.x >> 2;    // h' tile 0..63
    const int b0  = bt * BT;
    const int g0  = j * HPc;

    // ---- one-time: split W_hh|W_ih into 3 bf16 planes (swizzled c4 ^= row&7) ----
    for (int idx = tid; idx < NG * 544; idx += NT) {
        int row = idx / 544, k = idx - row * 544;
        int grow = (row < 8) ? g0 + row : (row < 16 ? Hsz + g0 + row - 8 : 2 * Hsz + g0 + row - 16);
        float v;
        if (k < Hsz) v = W_hh[(size_t)grow * Hsz + k];
        else { int vv = k - Hsz; v = (vv < Vsz) ? W_ih[grow * Vsz + vv] : 0.f; }
        unsigned short t1 = btrunc(v); float r1 = v - bup(t1);
        unsigned short t2 = btrunc(r1); float r2 = r1 - bup(t2);
        unsigned short t3 = btrunc(r2);
        int off = row * WROW + (((k >> 3) ^ (row & 7)) << 3) + (k & 7);
        Wp0[off] = t1; Wp1[off] = t2; Wp2[off] = t3;
    }
    for (int idx = tid; idx < Vsz * Hsz; idx += NT) {
        int row = idx >> 9, k = idx & 511;
        int off = row * WDROW + (((k >> 3) ^ (row & 7)) << 3) + (k & 7);
        Wdp[off] = brne(W_dec[(size_t)row * Hsz + k]);
    }
    if (tid < NG) {
        int grow = (tid < 8) ? g0 + tid : (tid < 16 ? Hsz + g0 + tid - 8 : 2 * Hsz + g0 + tid - 16);
        bihL[tid] = b_ih[grow]; bhhL[tid] = b_hh[grow];
    }

    const int w   = tid >> 6;        // wave id = M-tile (batch rows w*16..w*16+16)
    const int ln  = tid & 63;
    const int cc  = ln & 15;         // frag row/col selector
    const int qq  = ln >> 4;         // K-quarter within K-step
    const int rowA = (w << 4) + cc;  // A-frag source row in chunk
    const int swzA0 = ((qq << 1) ^ (cc & 7));
    const int swzA1 = (((qq << 1) | 1) ^ (cc & 7));
    int wr0 = cc;                                   // B rows (r,z tile): 0..15 valid
    int wr1 = 16 + cc; if (wr1 >= NG) wr1 = 0;      // n-gate tile: clamp pad rows
    int dr1 = 16 + cc; if (dr1 >= Vsz) dr1 = 0;     // decode tile1 clamp
    const float bd0 = b_dec[cc];
    const float bd1 = (16 + cc < Vsz) ? b_dec[16 + cc] : 0.f;
    unsigned* mycnt = cnt + bt;
    // global_load_lds mapping: slot s=2w,2w+1; lane -> row s*8+(ln>>3), phys c4 = ln&7,
    // logical c4 = (ln&7)^(ln>>3)  (inverse-swizzled source, linear LDS dest)
    const int ldr0 = (w << 4) + (ln >> 3);
    const int ldr1 = (w << 4) + 8 + (ln >> 3);
    const int gc4  = (ln & 7) ^ (ln >> 3);

    __syncthreads();   // planes ready

    for (int i = 0; i <= Tsz; ++i) {
        const float* hprev = hbuf + (size_t)(i & 1) * (Bsz * Hsz);
        float* hnext = hbuf + (size_t)((i + 1) & 1) * (Bsz * Hsz);

        // stage chunk 0
        gload_lds16(hprev + (size_t)(b0 + ldr0) * Hsz + (gc4 << 2), &Abuf[0][(w << 9)]);
        gload_lds16(hprev + (size_t)(b0 + ldr1) * Hsz + (gc4 << 2), &Abuf[0][(w << 9) + 256]);
        __syncthreads();

        f32x4 accRZ = {0.f,0.f,0.f,0.f}, accNh = {0.f,0.f,0.f,0.f}, accNi = {0.f,0.f,0.f,0.f};
        f32x4 accD0 = {0.f,0.f,0.f,0.f}, accD1 = {0.f,0.f,0.f,0.f};

        for (int c = 0; c < 17; ++c) {
            if (c < 15) {   // prefetch next h chunk
                gload_lds16(hprev + (size_t)(b0 + ldr0) * Hsz + ((c + 1) << 5) + (gc4 << 2),
                            &Abuf[(c + 1) & 1][(w << 9)]);
                gload_lds16(hprev + (size_t)(b0 + ldr1) * Hsz + ((c + 1) << 5) + (gc4 << 2),
                            &Abuf[(c + 1) & 1][(w << 9) + 256]);
            }
            if (c == 15 && i < Tsz) {   // stage x_i into Abuf[0] (read at c==16)
                for (int idx = tid; idx < BT * Vsz; idx += NT) {
                    int r = idx / Vsz, v = idx - r * Vsz;
                    Abuf[0][r * 32 + (((v >> 2) ^ (r & 7)) << 2) + (v & 3)] =
                        x[(size_t)(b0 + r) * (Tsz * Vsz) + (size_t)i * Vsz + v];
                }
            }
            // A-frag: 8 fp32 -> triple bf16 split
            const float* Ab = Abuf[c & 1];
            f32x4 fa = *(const f32x4*)&Ab[rowA * 32 + (swzA0 << 2)];
            f32x4 fb = *(const f32x4*)&Ab[rowA * 32 + (swzA1 << 2)];
            s16x8 A1, A2, A3;
            #pragma unroll
            for (int e = 0; e < 8; ++e) {
                float v = (e < 4) ? fa[e & 3] : fb[e & 3];
                unsigned short s1 = btrunc(v); float r1 = v - bup(s1);
                unsigned short s2 = btrunc(r1); float r2 = r1 - bup(s2);
                unsigned short s3 = btrunc(r2);
                A1[e] = (short)s1; A2[e] = (short)s2; A3[e] = (short)s3;
            }
            const int bc4 = (c << 2) + qq;
            {   // N-tile 0: r,z gates (K=544 incl. folded x-projection)
                int o = wr0 * WROW + ((bc4 ^ (wr0 & 7)) << 3);
                s16x8 B1 = *(const s16x8*)&Wp0[o];
                s16x8 B2 = *(const s16x8*)&Wp1[o];
                s16x8 B3 = *(const s16x8*)&Wp2[o];
                accRZ = MFMA(A1, B1, accRZ, 0, 0, 0);
                accRZ = MFMA(A1, B2, accRZ, 0, 0, 0);
                accRZ = MFMA(A2, B1, accRZ, 0, 0, 0);
                accRZ = MFMA(A1, B3, accRZ, 0, 0, 0);
                accRZ = MFMA(A2, B2, accRZ, 0, 0, 0);
                accRZ = MFMA(A3, B1, accRZ, 0, 0, 0);
            }
            {   // N-tile 1: n-gate. h-part (c<16) and x-part (c==16) kept separate.
                int o = wr1 * WROW + ((bc4 ^ (wr1 & 7)) << 3);
                s16x8 B1 = *(const s16x8*)&Wp0[o];
                s16x8 B2 = *(const s16x8*)&Wp1[o];
                s16x8 B3 = *(const s16x8*)&Wp2[o];
                if (c < 16) {
                    accNh = MFMA(A1, B1, accNh, 0, 0, 0);
                    accNh = MFMA(A1, B2, accNh, 0, 0, 0);
                    accNh = MFMA(A2, B1, accNh, 0, 0, 0);
                    accNh = MFMA(A1, B3, accNh, 0, 0, 0);
                    accNh = MFMA(A2, B2, accNh, 0, 0, 0);
                    accNh = MFMA(A3, B1, accNh, 0, 0, 0);
                } else {
                    accNi = MFMA(A1, B1, accNi, 0, 0, 0);
                    accNi = MFMA(A1, B2, accNi, 0, 0, 0);
                    accNi = MFMA(A2, B1, accNi, 0, 0, 0);
                    accNi = MFMA(A1, B3, accNi, 0, 0, 0);
                    accNi = MFMA(A2, B2, accNi, 0, 0, 0);
                    accNi = MFMA(A3, B1, accNi, 0, 0, 0);
                }
            }
            if (c < 16) {   // fused decode of h_i (K=512 only)
                int o0 = cc * WDROW + ((bc4 ^ (cc & 7)) << 3);
                s16x8 D1 = *(const s16x8*)&Wdp[o0];
                accD0 = MFMA(A1, D1, accD0, 0, 0, 0);
                accD0 = MFMA(A2, D1, accD0, 0, 0, 0);
                int o1 = dr1 * WDROW + ((bc4 ^ (dr1 & 7)) << 3);
                s16x8 D2 = *(const s16x8*)&Wdp[o1];
                accD1 = MFMA(A1, D2, accD1, 0, 0, 0);
                accD1 = MFMA(A2, D2, accD1, 0, 0, 0);
            }
            __syncthreads();
        }

        // z-gate values live on lane cc+8 of the same row-quad; pull before divergence
        float zsh[4];
        #pragma unroll
        for (int r = 0; r < 4; ++r)
            zsh[r] = __shfl(accRZ[r], (ln & 48) | (cc + 8));

        if (i < Tsz && cc < 8) {
            float hk[4];
            #pragma unroll
            for (int r = 0; r < 4; ++r)
                hk[r] = hprev[(size_t)(b0 + (w << 4) + (qq << 2) + r) * Hsz + g0 + cc];
            #pragma unroll
            for (int r = 0; r < 4; ++r) {
                float rv = accRZ[r] + bihL[cc] + bhhL[cc];
                float zv = zsh[r] + bihL[8 + cc] + bhhL[8 + cc];
                float nh = accNh[r] + bhhL[16 + cc];
                float ni = accNi[r] + bihL[16 + cc];
                float rg = 1.f / (1.f + expf(-rv));
                float zg = 1.f / (1.f + expf(-zv));
                float ng = tanhf(ni + rg * nh);
                store_wt(&hnext[(size_t)(b0 + (w << 4) + (qq << 2) + r) * Hsz + g0 + cc],
                         (1.f - zg) * ng + zg * hk[r]);
            }
        }
        if (i > 0) {   // logits[:, i-1, :] from h_i
            #pragma unroll
            for (int r = 0; r < 4; ++r) {
                size_t brow = (size_t)(b0 + (w << 4) + (qq << 2) + r);
                out[brow * (Tsz * Vsz) + (size_t)(i - 1) * Vsz + cc] = accD0[r] + bd0;
                if (16 + cc < Vsz)
                    out[brow * (Tsz * Vsz) + (size_t)(i - 1) * Vsz + 16 + cc] = accD1[r] + bd1;
            }
        }
        if (i < Tsz) {
            asm volatile("s_waitcnt vmcnt(0)" ::: "memory");   // WT h-stores at L3
            group_barrier(mycnt, 64u * (unsigned)(i + 1));
        }
    }
}

extern "C" void kernel_launch(void* const* d_in, const int* in_sizes, int n_in,
                              void* d_out, int out_size, void* d_ws, size_t ws_size,
                              hipStream_t stream) {
    const float* x     = (const float*)d_in[0];
    const float* W_ih  = (const float*)d_in[1];
    const float* W_hh  = (const float*)d_in[2];
    const float* b_ih  = (const float*)d_in[3];
    const float* b_hh  = (const float*)d_in[4];
    const float* W_dec = (const float*)d_in[5];
    const float* b_dec = (const float*)d_in[6];
    float* out  = (float*)d_out;
    float* hbuf = (float*)d_ws;                                    // 2 x 1 MB h double buffer
    unsigned* cnt = (unsigned*)((char*)d_ws + (size_t)2 * Bsz * Hsz * sizeof(float));

    init_ws_kernel<<<256, 256, 0, stream>>>(hbuf, cnt);

    // Plain launch: ~140 KB LDS -> 1 block/CU, grid == 256 == CU count ->
    // all blocks co-resident; group barriers cannot deadlock (R4/R6-proven).
    gru_persist<<<dim3(NBLK), dim3(NT), 0, stream>>>(
        x, W_ih, W_hh, b_ih, b_hh, W_dec, b_dec, hbuf, cnt, out);
}

// Round 8
// 21901.944 us; speedup vs baseline: 3.2388x; 1.1843x over previous
//
#include <hip/hip_runtime.h>
#include <math.h>

#define Bsz 512
#define Tsz 1024
#define Vsz 27
#define Hsz 512
#define BH (Bsz * Hsz)
#define NBLK 256
#define NT 512      // 8 waves; wave = M-tile (16 batch rows)
#define BT 128      // batch rows per group (4 groups x 64 j-blocks)
#define HPc 8       // h' cols per block
#define NG 24       // 3*HPc gate rows per block
#define WROW 576    // ushort stride of W planes (covers swizzled c4 to 71)
#define WDROW 512
#define XSTR 36     // xs row stride (floats): 144B, 16B-aligned, 2-way banks max

typedef float f32x4 __attribute__((ext_vector_type(4)));
typedef short s16x8 __attribute__((ext_vector_type(8)));
#define MFMA __builtin_amdgcn_mfma_f32_16x16x32_bf16

__device__ __forceinline__ unsigned short btrunc(float x) {   // bf16 RTZ bits
    return (unsigned short)(__float_as_uint(x) >> 16);
}
__device__ __forceinline__ float bup(unsigned short b) {
    return __uint_as_float(((unsigned)b) << 16);
}
__device__ __forceinline__ unsigned short brne(float x) {     // bf16 RNE bits
    unsigned u = __float_as_uint(x);
    return (unsigned short)((u + 0x7FFFu + ((u >> 16) & 1u)) >> 16);
}
// write-through: h planes never dirty in any XCD L2 -> L3 always current (R6/R7-proven)
__device__ __forceinline__ void store_wt_s(unsigned short* p, unsigned short v) {
    unsigned vv = v;
    asm volatile("global_store_short %0, %1, off sc0 sc1" :: "v"(p), "v"(vv) : "memory");
}

__global__ void init_ws_kernel(unsigned short* __restrict__ hpl, unsigned* __restrict__ cnt) {
    size_t i = (size_t)blockIdx.x * 256 + threadIdx.x;   // 768 blk x 256 thr x 16B = 3 MB
    ((uint4*)hpl)[i] = make_uint4(0u, 0u, 0u, 0u);
    if (blockIdx.x == 0) cnt[threadIdx.x] = 0u;
}

// Relaxed add + relaxed poll + ONE acquire fence after spin (R7-proven).
__device__ __forceinline__ void group_barrier(unsigned* c, unsigned target) {
    __syncthreads();
    if (threadIdx.x == 0) {
        __hip_atomic_fetch_add(c, 1u, __ATOMIC_RELAXED, __HIP_MEMORY_SCOPE_AGENT);
        while (__hip_atomic_load(c, __ATOMIC_RELAXED, __HIP_MEMORY_SCOPE_AGENT) < target)
            __builtin_amdgcn_s_sleep(2);
        __threadfence();   // acquire: invalidate stale L1/L2 once per step
    }
    __syncthreads();
}

__global__ __launch_bounds__(NT, 2) void gru_persist(
    const float* __restrict__ x, const float* __restrict__ W_ih,
    const float* __restrict__ W_hh, const float* __restrict__ b_ih,
    const float* __restrict__ b_hh, const float* __restrict__ W_dec,
    const float* __restrict__ b_dec, unsigned short* __restrict__ hpl,
    unsigned* __restrict__ cnt, float* __restrict__ out)
{
    // bf16 triple-split W planes, K = 544 (512 h | 27 x | 5 zero)
    __shared__ unsigned short Wp0[NG * WROW], Wp1[NG * WROW], Wp2[NG * WROW];
    __shared__ unsigned short Wdp[Vsz * WDROW];
    __shared__ float xs[BT][XSTR];
    __shared__ float bihL[NG], bhhL[NG];

    const int tid = threadIdx.x;
    const int bt  = blockIdx.x & 3;     // batch group 0..3
    const int j   = blockIdx.x >> 2;    // h' tile 0..63
    const int b0  = bt * BT;
    const int g0  = j * HPc;

    // ---- one-time: split W_hh|W_ih into 3 bf16 planes (swizzle c4 ^= row&7) ----
    for (int idx = tid; idx < NG * 544; idx += NT) {
        int row = idx / 544, k = idx - row * 544;
        int grow = (row < 8) ? g0 + row : (row < 16 ? Hsz + g0 + row - 8 : 2 * Hsz + g0 + row - 16);
        float v;
        if (k < Hsz) v = W_hh[(size_t)grow * Hsz + k];
        else { int vv = k - Hsz; v = (vv < Vsz) ? W_ih[grow * Vsz + vv] : 0.f; }
        unsigned short t1 = btrunc(v); float r1 = v - bup(t1);
        unsigned short t2 = btrunc(r1); float r2 = r1 - bup(t2);
        unsigned short t3 = btrunc(r2);
        int off = row * WROW + (((k >> 3) ^ (row & 7)) << 3) + (k & 7);
        Wp0[off] = t1; Wp1[off] = t2; Wp2[off] = t3;
    }
    for (int idx = tid; idx < Vsz * Hsz; idx += NT) {
        int row = idx >> 9, k = idx & 511;
        int off = row * WDROW + (((k >> 3) ^ (row & 7)) << 3) + (k & 7);
        Wdp[off] = brne(W_dec[(size_t)row * Hsz + k]);
    }
    if (tid < NG) {
        int grow = (tid < 8) ? g0 + tid : (tid < 16 ? Hsz + g0 + tid - 8 : 2 * Hsz + g0 + tid - 16);
        bihL[tid] = b_ih[grow]; bhhL[tid] = b_hh[grow];
    }

    const int w   = tid >> 6;          // wave id = M-tile
    const int ln  = tid & 63;
    const int cc  = ln & 15;
    const int qq  = ln >> 4;
    const int rowA = (w << 4) + cc;    // batch row within group tile
    int wr0 = cc;
    int wr1 = 16 + cc; if (wr1 >= NG) wr1 = 0;
    int dr1 = 16 + cc; if (dr1 >= Vsz) dr1 = 0;
    const float bd0 = b_dec[cc];
    const float bd1 = (16 + cc < Vsz) ? b_dec[16 + cc] : 0.f;
    unsigned* mycnt = cnt + bt;

    __syncthreads();   // planes ready

    for (int i = 0; i <= Tsz; ++i) {
        const unsigned short* hr = hpl + (size_t)(i & 1) * 3 * BH;
        unsigned short*       hw = hpl + (size_t)((i + 1) & 1) * 3 * BH;

        // stage x_i (zero-padded to 32 cols)
        if (i < Tsz) {
            for (int idx = tid; idx < BT * 32; idx += NT) {
                int r = idx >> 5, v = idx & 31;
                xs[r][v] = (v < Vsz) ? x[(size_t)(b0 + r) * (Tsz * Vsz) + (size_t)i * Vsz + v] : 0.f;
            }
        }
        __syncthreads();

        // hkeep: reconstruct own h' slice from planes (exact to 2^-24)
        float hk[4] = {0.f, 0.f, 0.f, 0.f};
        if (cc < 8 && i < Tsz) {
            #pragma unroll
            for (int r = 0; r < 4; ++r) {
                size_t e = (size_t)(b0 + (w << 4) + (qq << 2) + r) * Hsz + g0 + cc;
                hk[r] = bup(hr[e]) + bup(hr[BH + e]) + bup(hr[2 * BH + e]);
            }
        }

        f32x4 accRZ = {0.f,0.f,0.f,0.f}, accNh = {0.f,0.f,0.f,0.f}, accNi = {0.f,0.f,0.f,0.f};
        f32x4 accD0 = {0.f,0.f,0.f,0.f}, accD1 = {0.f,0.f,0.f,0.f};

        // A-fragment base for this lane: row rowA, k = c*32 + qq*8 (ushorts)
        const unsigned short* abase = hr + (size_t)(b0 + rowA) * Hsz + (qq << 3);

        #pragma unroll
        for (int c = 0; c < 16; ++c) {
            const unsigned short* ap = abase + (c << 5);
            s16x8 A1 = *(const s16x8*)(ap);
            s16x8 A2 = *(const s16x8*)(ap + BH);
            s16x8 A3 = *(const s16x8*)(ap + 2 * BH);
            const int bc4 = (c << 2) + qq;
            {   // N-tile 0: r,z gates
                int o = wr0 * WROW + ((bc4 ^ (wr0 & 7)) << 3);
                s16x8 B1 = *(const s16x8*)&Wp0[o];
                s16x8 B2 = *(const s16x8*)&Wp1[o];
                s16x8 B3 = *(const s16x8*)&Wp2[o];
                accRZ = MFMA(A1, B1, accRZ, 0, 0, 0);
                accRZ = MFMA(A1, B2, accRZ, 0, 0, 0);
                accRZ = MFMA(A2, B1, accRZ, 0, 0, 0);
                accRZ = MFMA(A1, B3, accRZ, 0, 0, 0);
                accRZ = MFMA(A2, B2, accRZ, 0, 0, 0);
                accRZ = MFMA(A3, B1, accRZ, 0, 0, 0);
            }
            {   // N-tile 1: n-gate h-part
                int o = wr1 * WROW + ((bc4 ^ (wr1 & 7)) << 3);
                s16x8 B1 = *(const s16x8*)&Wp0[o];
                s16x8 B2 = *(const s16x8*)&Wp1[o];
                s16x8 B3 = *(const s16x8*)&Wp2[o];
                accNh = MFMA(A1, B1, accNh, 0, 0, 0);
                accNh = MFMA(A1, B2, accNh, 0, 0, 0);
                accNh = MFMA(A2, B1, accNh, 0, 0, 0);
                accNh = MFMA(A1, B3, accNh, 0, 0, 0);
                accNh = MFMA(A2, B2, accNh, 0, 0, 0);
                accNh = MFMA(A3, B1, accNh, 0, 0, 0);
            }
            {   // fused decode of h_i
                int o0 = cc * WDROW + ((bc4 ^ (cc & 7)) << 3);
                s16x8 D1 = *(const s16x8*)&Wdp[o0];
                accD0 = MFMA(A1, D1, accD0, 0, 0, 0);
                accD0 = MFMA(A2, D1, accD0, 0, 0, 0);
                int o1 = dr1 * WDROW + ((bc4 ^ (dr1 & 7)) << 3);
                s16x8 D2 = *(const s16x8*)&Wdp[o1];
                accD1 = MFMA(A1, D2, accD1, 0, 0, 0);
                accD1 = MFMA(A2, D2, accD1, 0, 0, 0);
            }
        }

        // K-chunk 16: fold x-projection (split fp32 x from LDS)
        if (i < Tsz) {
            f32x4 fa = *(const f32x4*)&xs[rowA][qq << 3];
            f32x4 fb = *(const f32x4*)&xs[rowA][(qq << 3) + 4];
            s16x8 A1, A2, A3;
            #pragma unroll
            for (int e = 0; e < 8; ++e) {
                float v = (e < 4) ? fa[e & 3] : fb[e & 3];
                unsigned short s1 = btrunc(v); float r1 = v - bup(s1);
                unsigned short s2 = btrunc(r1); float r2 = r1 - bup(s2);
                unsigned short s3 = btrunc(r2);
                A1[e] = (short)s1; A2[e] = (short)s2; A3[e] = (short)s3;
            }
            const int bc4 = 64 + qq;
            {   // r,z gates x-part (folds into same accRZ)
                int o = wr0 * WROW + ((bc4 ^ (wr0 & 7)) << 3);
                s16x8 B1 = *(const s16x8*)&Wp0[o];
                s16x8 B2 = *(const s16x8*)&Wp1[o];
                s16x8 B3 = *(const s16x8*)&Wp2[o];
                accRZ = MFMA(A1, B1, accRZ, 0, 0, 0);
                accRZ = MFMA(A1, B2, accRZ, 0, 0, 0);
                accRZ = MFMA(A2, B1, accRZ, 0, 0, 0);
                accRZ = MFMA(A1, B3, accRZ, 0, 0, 0);
                accRZ = MFMA(A2, B2, accRZ, 0, 0, 0);
                accRZ = MFMA(A3, B1, accRZ, 0, 0, 0);
            }
            {   // n-gate x-part (separate accumulator per GRU semantics)
                int o = wr1 * WROW + ((bc4 ^ (wr1 & 7)) << 3);
                s16x8 B1 = *(const s16x8*)&Wp0[o];
                s16x8 B2 = *(const s16x8*)&Wp1[o];
                s16x8 B3 = *(const s16x8*)&Wp2[o];
                accNi = MFMA(A1, B1, accNi, 0, 0, 0);
                accNi = MFMA(A1, B2, accNi, 0, 0, 0);
                accNi = MFMA(A2, B1, accNi, 0, 0, 0);
                accNi = MFMA(A1, B3, accNi, 0, 0, 0);
                accNi = MFMA(A2, B2, accNi, 0, 0, 0);
                accNi = MFMA(A3, B1, accNi, 0, 0, 0);
            }
        }

        // z-gate lives on lane cc+8 of same qq-quad
        float zsh[4];
        #pragma unroll
        for (int r = 0; r < 4; ++r)
            zsh[r] = __shfl(accRZ[r], (ln & 48) | (cc + 8));

        if (i < Tsz && cc < 8) {
            #pragma unroll
            for (int r = 0; r < 4; ++r) {
                float rv = accRZ[r] + bihL[cc] + bhhL[cc];
                float zv = zsh[r] + bihL[8 + cc] + bhhL[8 + cc];
                float nh = accNh[r] + bhhL[16 + cc];
                float ni = accNi[r] + bihL[16 + cc];
                float rg = 1.f / (1.f + expf(-rv));
                float zg = 1.f / (1.f + expf(-zv));
                float ng = tanhf(ni + rg * nh);
                float hv = (1.f - zg) * ng + zg * hk[r];
                size_t e = (size_t)(b0 + (w << 4) + (qq << 2) + r) * Hsz + g0 + cc;
                unsigned short s1 = btrunc(hv); float r1 = hv - bup(s1);
                unsigned short s2 = btrunc(r1); float r2 = r1 - bup(s2);
                unsigned short s3 = btrunc(r2);
                store_wt_s(&hw[e], s1);
                store_wt_s(&hw[BH + e], s2);
                store_wt_s(&hw[2 * BH + e], s3);
            }
        }
        if (i > 0) {   // logits[:, i-1, :] from h_i
            #pragma unroll
            for (int r = 0; r < 4; ++r) {
                size_t brow = (size_t)(b0 + (w << 4) + (qq << 2) + r);
                out[brow * (Tsz * Vsz) + (size_t)(i - 1) * Vsz + cc] = accD0[r] + bd0;
                if (16 + cc < Vsz)
                    out[brow * (Tsz * Vsz) + (size_t)(i - 1) * Vsz + 16 + cc] = accD1[r] + bd1;
            }
        }
        if (i < Tsz) {
            asm volatile("s_waitcnt vmcnt(0)" ::: "memory");   // WT h-stores at L3
            group_barrier(mycnt, 64u * (unsigned)(i + 1));
        }
    }
}

extern "C" void kernel_launch(void* const* d_in, const int* in_sizes, int n_in,
                              void* d_out, int out_size, void* d_ws, size_t ws_size,
                              hipStream_t stream) {
    const float* x     = (const float*)d_in[0];
    const float* W_ih  = (const float*)d_in[1];
    const float* W_hh  = (const float*)d_in[2];
    const float* b_ih  = (const float*)d_in[3];
    const float* b_hh  = (const float*)d_in[4];
    const float* W_dec = (const float*)d_in[5];
    const float* b_dec = (const float*)d_in[6];
    float* out  = (float*)d_out;
    unsigned short* hpl = (unsigned short*)d_ws;   // 2 bufs x 3 planes x 512KB = 3 MB
    unsigned* cnt = (unsigned*)((char*)d_ws + (size_t)2 * 3 * BH * sizeof(unsigned short));

    init_ws_kernel<<<768, 256, 0, stream>>>(hpl, cnt);

    // Plain launch: ~129 KB LDS -> 1 block/CU, grid == 256 == CU count ->
    // all blocks co-resident; group barriers cannot deadlock (R4/R6/R7-proven).
    gru_persist<<<dim3(NBLK), dim3(NT), 0, stream>>>(
        x, W_ih, W_hh, b_ih, b_hh, W_dec, b_dec, hpl, cnt, out);
}

// Round 10
// 16736.259 us; speedup vs baseline: 4.2385x; 1.3087x over previous
//
#include <hip/hip_runtime.h>
#include <math.h>

#define Bsz 512
#define Tsz 1024
#define Vsz 27
#define Hsz 512
#define BH (Bsz * Hsz)
#define TV (Tsz * Vsz)
#define NBLK 256
#define NT 512      // 8 waves; wave = M-tile (16 batch rows)
#define BT 128      // batch rows per group (4 groups x 64 j-blocks)
#define HPc 8       // h' cols per block
#define NG 24       // gate rows per block (8r + 8z + 8n)
#define XSTR 36     // xs row stride (floats)
#define CPOL 0x11   // sc0|sc1: coherence-point access, bypass L1/L2

typedef float f32x4 __attribute__((ext_vector_type(4)));
typedef short s16x8 __attribute__((ext_vector_type(8)));
typedef unsigned int u32x4 __attribute__((ext_vector_type(4)));
#define MFMA __builtin_amdgcn_mfma_f32_16x16x32_bf16

__device__ __forceinline__ unsigned short btrunc(float x) {   // bf16 RTZ bits
    return (unsigned short)(__float_as_uint(x) >> 16);
}
__device__ __forceinline__ float bup(unsigned short b) {
    return __uint_as_float(((unsigned)b) << 16);
}
__device__ __forceinline__ unsigned short brne(float x) {     // bf16 RNE bits
    unsigned u = __float_as_uint(x);
    return (unsigned short)((u + 0x7FFFu + ((u >> 16) & 1u)) >> 16);
}
// ROCm7: raw_buffer builtins take the opaque __amdgpu_buffer_rsrc_t
__device__ __forceinline__ __amdgpu_buffer_rsrc_t make_rsrc(void* p, unsigned bytes) {
    return __builtin_amdgcn_make_buffer_rsrc(p, (short)0, (int)bytes, 0x00020000);
}
__device__ __forceinline__ s16x8 bload128(__amdgpu_buffer_rsrc_t rsrc, int voff) {
    u32x4 d = __builtin_amdgcn_raw_buffer_load_b128(rsrc, voff, 0, CPOL);
    return __builtin_bit_cast(s16x8, d);
}

__global__ void init_ws_kernel(unsigned short* __restrict__ hpl, unsigned* __restrict__ cnt) {
    size_t i = (size_t)blockIdx.x * 256 + threadIdx.x;   // 768 x 256 x 16B = 3 MB
    ((uint4*)hpl)[i] = make_uint4(0u, 0u, 0u, 0u);
    if (blockIdx.x == 0) cnt[threadIdx.x] = 0u;
}

// Fence-free barrier (R6-proven): h moves via sc0sc1 write-through stores +
// sc0sc1 bypass loads (always coherence-point-current); flag via agent
// atomics. NO threadfence -> L2 never invalidated -> x/weights stay warm.
__device__ __forceinline__ void group_barrier(unsigned* c, unsigned target) {
    __syncthreads();
    if (threadIdx.x == 0) {
        __hip_atomic_fetch_add(c, 1u, __ATOMIC_RELAXED, __HIP_MEMORY_SCOPE_AGENT);
        while (__hip_atomic_load(c, __ATOMIC_RELAXED, __HIP_MEMORY_SCOPE_AGENT) < target)
            __builtin_amdgcn_s_sleep(2);
    }
    __syncthreads();
}

__global__ __launch_bounds__(NT, 2) void gru_persist(
    const float* __restrict__ x, const float* __restrict__ W_ih,
    const float* __restrict__ W_hh, const float* __restrict__ b_ih,
    const float* __restrict__ b_hh, const float* __restrict__ W_dec,
    const float* __restrict__ b_dec, unsigned short* __restrict__ hpl,
    unsigned* __restrict__ cnt, float* __restrict__ out)
{
    // Fragment-linear streams: every ds_read_b128 is lane-contiguous 1KB.
    __shared__ unsigned short Bst[17 * 6 * 512];   // [c][tile][plane][ln][8] 102KB
    __shared__ unsigned short Dst[16 * 512];       // decode stream (j<2)     16KB
    __shared__ float xs[BT][XSTR];
    __shared__ float bihL[NG], bhhL[NG];

    const int tid = threadIdx.x;
    const int bt  = blockIdx.x & 3;     // batch group 0..3
    const int j   = blockIdx.x >> 2;    // h' tile 0..63
    const int b0  = bt * BT;
    const int g0  = j * HPc;

    // ---- one-time: build B-stream (triple-split W, fragment order) ----
    for (int idx = tid; idx < 17 * 6 * 512; idx += NT) {
        int e   = idx & 7;
        int ln2 = (idx >> 3) & 63;
        int rem = idx >> 9;            // (c*2+t)*3+p
        int p   = rem % 3;
        int ct  = rem / 3;
        int t   = ct & 1;
        int c   = ct >> 1;
        int cc2 = ln2 & 15, qq2 = ln2 >> 4;
        int k = c * 32 + qq2 * 8 + e;
        float v = 0.f;
        int grow = (t == 0) ? ((cc2 < 8) ? (g0 + cc2) : (Hsz + g0 + cc2 - 8))
                            : ((cc2 < 8) ? (2 * Hsz + g0 + cc2) : -1);
        if (grow >= 0) {
            if (k < Hsz) v = W_hh[(size_t)grow * Hsz + k];
            else if (k - Hsz < Vsz) v = W_ih[grow * Vsz + (k - Hsz)];
        }
        unsigned short t1 = btrunc(v); float r1 = v - bup(t1);
        unsigned short t2 = btrunc(r1); float r2 = r1 - bup(t2);
        unsigned short t3 = btrunc(r2);
        Bst[idx] = (p == 0) ? t1 : (p == 1) ? t2 : t3;
    }
    if (j < 2) {
        for (int idx = tid; idx < 16 * 512; idx += NT) {
            int e = idx & 7; int ln2 = (idx >> 3) & 63; int c = idx >> 9;
            int cc2 = ln2 & 15, qq2 = ln2 >> 4;
            int k = c * 32 + qq2 * 8 + e;
            int vr = (j == 0) ? cc2 : 16 + cc2;
            Dst[idx] = (vr < Vsz) ? brne(W_dec[(size_t)vr * Hsz + k]) : (unsigned short)0;
        }
    }
    if (tid < NG) {
        int grow = (tid < 8) ? g0 + tid : (tid < 16 ? Hsz + g0 + tid - 8 : 2 * Hsz + g0 + tid - 16);
        bihL[tid] = b_ih[grow]; bhhL[tid] = b_hh[grow];
    }

    const int w   = tid >> 6;          // wave id = M-tile
    const int ln  = tid & 63;
    const int cc  = ln & 15;
    const int qq  = ln >> 4;
    const int rowA = (w << 4) + cc;
    const int xr = tid >> 2, xc = (tid & 3) << 3;
    const int vcol = (j == 0) ? cc : 16 + cc;     // decode column (j<2)
    const float bdv = (j < 2 && vcol < Vsz) ? b_dec[vcol] : 0.f;
    unsigned* mycnt = cnt + bt;
    const __amdgpu_buffer_rsrc_t hrs = make_rsrc((void*)hpl, 2u * 3u * BH * 2u);

    // x_0 staging
    {
        #pragma unroll
        for (int e = 0; e < 8; ++e) {
            int ci = xc + e;
            xs[xr][ci] = (ci < Vsz) ? x[(size_t)(b0 + xr) * TV + ci] : 0.f;
        }
    }
    float hk[4] = {0.f, 0.f, 0.f, 0.f};   // own h' slice carried in regs (h_0=0)
    __syncthreads();

    for (int i = 0; i <= Tsz; ++i) {
        // prefetch x_{i+1} to regs (plain loads; x is read-only -> L2 fine)
        float xreg[8];
        if (i + 1 < Tsz) {
            #pragma unroll
            for (int e = 0; e < 8; ++e) {
                int ci = xc + e;
                xreg[e] = (ci < Vsz) ? x[(size_t)(b0 + xr) * TV + (size_t)(i + 1) * Vsz + ci] : 0.f;
            }
        }

        const int par = (i & 1) * (3 * BH * 2);
        const int voffA0 = par + (((b0 + rowA) * Hsz + (qq << 3)) << 1);

        f32x4 accRZ = {0.f,0.f,0.f,0.f}, accNh = {0.f,0.f,0.f,0.f};
        f32x4 accNi = {0.f,0.f,0.f,0.f}, accD  = {0.f,0.f,0.f,0.f};

        #pragma unroll
        for (int c = 0; c < 16; ++c) {
            s16x8 A1 = bload128(hrs, voffA0 + c * 64);
            s16x8 A2 = bload128(hrs, voffA0 + c * 64 + BH * 2);
            s16x8 A3 = bload128(hrs, voffA0 + c * 64 + 2 * BH * 2);
            const unsigned short* bs = Bst + c * (6 * 512) + (ln << 3);
            {   // tile0: r,z gates
                s16x8 B1 = *(const s16x8*)(bs);
                s16x8 B2 = *(const s16x8*)(bs + 512);
                s16x8 B3 = *(const s16x8*)(bs + 1024);
                accRZ = MFMA(A1, B1, accRZ, 0, 0, 0);
                accRZ = MFMA(A1, B2, accRZ, 0, 0, 0);
                accRZ = MFMA(A2, B1, accRZ, 0, 0, 0);
                accRZ = MFMA(A1, B3, accRZ, 0, 0, 0);
                accRZ = MFMA(A2, B2, accRZ, 0, 0, 0);
                accRZ = MFMA(A3, B1, accRZ, 0, 0, 0);
            }
            {   // tile1: n-gate h-part
                s16x8 C1 = *(const s16x8*)(bs + 1536);
                s16x8 C2 = *(const s16x8*)(bs + 2048);
                s16x8 C3 = *(const s16x8*)(bs + 2560);
                accNh = MFMA(A1, C1, accNh, 0, 0, 0);
                accNh = MFMA(A1, C2, accNh, 0, 0, 0);
                accNh = MFMA(A2, C1, accNh, 0, 0, 0);
                accNh = MFMA(A1, C3, accNh, 0, 0, 0);
                accNh = MFMA(A2, C2, accNh, 0, 0, 0);
                accNh = MFMA(A3, C1, accNh, 0, 0, 0);
            }
            if (j < 2) {   // fused decode of h_i (this block's v-rows only)
                s16x8 D1 = *(const s16x8*)(Dst + (c << 9) + (ln << 3));
                accD = MFMA(A1, D1, accD, 0, 0, 0);
                accD = MFMA(A2, D1, accD, 0, 0, 0);
            }
        }

        // K-chunk 16: fold x-projection (triple-split fp32 x from LDS)
        if (i < Tsz) {
            f32x4 fa = *(const f32x4*)&xs[rowA][qq << 3];
            f32x4 fb = *(const f32x4*)&xs[rowA][(qq << 3) + 4];
            s16x8 A1, A2, A3;
            #pragma unroll
            for (int e = 0; e < 8; ++e) {
                float v = (e < 4) ? fa[e & 3] : fb[e & 3];
                unsigned short s1 = btrunc(v); float r1 = v - bup(s1);
                unsigned short s2 = btrunc(r1); float r2 = r1 - bup(s2);
                unsigned short s3 = btrunc(r2);
                A1[e] = (short)s1; A2[e] = (short)s2; A3[e] = (short)s3;
            }
            const unsigned short* bs = Bst + 16 * (6 * 512) + (ln << 3);
            {   // r,z x-part
                s16x8 B1 = *(const s16x8*)(bs);
                s16x8 B2 = *(const s16x8*)(bs + 512);
                s16x8 B3 = *(const s16x8*)(bs + 1024);
                accRZ = MFMA(A1, B1, accRZ, 0, 0, 0);
                accRZ = MFMA(A1, B2, accRZ, 0, 0, 0);
                accRZ = MFMA(A2, B1, accRZ, 0, 0, 0);
                accRZ = MFMA(A1, B3, accRZ, 0, 0, 0);
                accRZ = MFMA(A2, B2, accRZ, 0, 0, 0);
                accRZ = MFMA(A3, B1, accRZ, 0, 0, 0);
            }
            {   // n-gate x-part (separate accumulator per GRU semantics)
                s16x8 C1 = *(const s16x8*)(bs + 1536);
                s16x8 C2 = *(const s16x8*)(bs + 2048);
                s16x8 C3 = *(const s16x8*)(bs + 2560);
                accNi = MFMA(A1, C1, accNi, 0, 0, 0);
                accNi = MFMA(A1, C2, accNi, 0, 0, 0);
                accNi = MFMA(A2, C1, accNi, 0, 0, 0);
                accNi = MFMA(A1, C3, accNi, 0, 0, 0);
                accNi = MFMA(A2, C2, accNi, 0, 0, 0);
                accNi = MFMA(A3, C1, accNi, 0, 0, 0);
            }
        }

        __syncthreads();                 // all x-folds done -> xs reusable
        if (i + 1 < Tsz) {
            #pragma unroll
            for (int e = 0; e < 8; ++e) xs[xr][xc + e] = xreg[e];
        }

        // z-gate lives on lane cc+8 of same qq-quad
        float zsh[4];
        #pragma unroll
        for (int r = 0; r < 4; ++r)
            zsh[r] = __shfl(accRZ[r], (ln & 48) | (cc + 8));

        if (i < Tsz && cc < 8) {
            const int wpar = ((i + 1) & 1) * (3 * BH * 2);
            #pragma unroll
            for (int r = 0; r < 4; ++r) {
                float rv = accRZ[r] + bihL[cc] + bhhL[cc];
                float zv = zsh[r] + bihL[8 + cc] + bhhL[8 + cc];
                float nh = accNh[r] + bhhL[16 + cc];
                float ni = accNi[r] + bihL[16 + cc];
                float rg = 1.f / (1.f + expf(-rv));
                float zg = 1.f / (1.f + expf(-zv));
                float ng = tanhf(ni + rg * nh);
                float hv = (1.f - zg) * ng + zg * hk[r];
                hk[r] = hv;   // own slice for next step, in regs
                int e2 = ((b0 + (w << 4) + (qq << 2) + r) * Hsz + g0 + cc) << 1;
                unsigned short s1 = btrunc(hv); float r1 = hv - bup(s1);
                unsigned short s2 = btrunc(r1); float r2 = r1 - bup(s2);
                unsigned short s3 = btrunc(r2);
                __builtin_amdgcn_raw_buffer_store_b16(s1, hrs, wpar + e2, 0, CPOL);
                __builtin_amdgcn_raw_buffer_store_b16(s2, hrs, wpar + e2 + BH * 2, 0, CPOL);
                __builtin_amdgcn_raw_buffer_store_b16(s3, hrs, wpar + e2 + 2 * BH * 2, 0, CPOL);
            }
        }
        if (i < Tsz) {
            // h write-through stores must reach the coherence point first
            asm volatile("s_waitcnt vmcnt(0)" ::: "memory");
            group_barrier(mycnt, 64u * (unsigned)(i + 1));
        }
        // logits[:, i-1, :] from h_i — after barrier, overlaps next K-loop
        if (i > 0 && j < 2 && vcol < Vsz) {
            #pragma unroll
            for (int r = 0; r < 4; ++r) {
                size_t brow = (size_t)(b0 + (w << 4) + (qq << 2) + r);
                out[brow * TV + (size_t)(i - 1) * Vsz + vcol] = accD[r] + bdv;
            }
        }
    }
}

extern "C" void kernel_launch(void* const* d_in, const int* in_sizes, int n_in,
                              void* d_out, int out_size, void* d_ws, size_t ws_size,
                              hipStream_t stream) {
    const float* x     = (const float*)d_in[0];
    const float* W_ih  = (const float*)d_in[1];
    const float* W_hh  = (const float*)d_in[2];
    const float* b_ih  = (const float*)d_in[3];
    const float* b_hh  = (const float*)d_in[4];
    const float* W_dec = (const float*)d_in[5];
    const float* b_dec = (const float*)d_in[6];
    float* out  = (float*)d_out;
    unsigned short* hpl = (unsigned short*)d_ws;   // 2 bufs x 3 planes x 512KB = 3 MB
    unsigned* cnt = (unsigned*)((char*)d_ws + (size_t)2 * 3 * BH * sizeof(unsigned short));

    init_ws_kernel<<<768, 256, 0, stream>>>(hpl, cnt);

    // Plain launch: ~136 KB LDS -> 1 block/CU, grid == 256 == CU count ->
    // all blocks co-resident; group barriers cannot deadlock (R4-R8-proven).
    gru_persist<<<dim3(NBLK), dim3(NT), 0, stream>>>(
        x, W_ih, W_hh, b_ih, b_hh, W_dec, b_dec, hpl, cnt, out);
}